// Round 8
// baseline (430.849 us; speedup 1.0000x reference)
//
#include <hip/hip_runtime.h>
#include <hip/hip_bf16.h>

typedef __hip_bfloat16 bf16;
typedef unsigned short u16;
typedef __attribute__((ext_vector_type(8))) short short8;
typedef __attribute__((ext_vector_type(4))) short s4v;
typedef __attribute__((ext_vector_type(4))) float f32x4;
typedef __attribute__((ext_vector_type(4))) unsigned int u32x4;

#define LEAK 0.1f
#define EPS_ 1e-5f
#define MFMA(a, b, c) __builtin_amdgcn_mfma_f32_16x16x32_bf16(a, b, c, 0, 0, 0)
// N=32 C=64 T=400 V=27 S=2 IC=16 O=64; P = T*V = 10800 per n.

__device__ __forceinline__ float u2f(u16 u) { return __uint_as_float(((unsigned int)u) << 16); }
__device__ __forceinline__ u16 f2u(float f) {
  bf16 h = __float2bfloat16(f);
  u16 r;
  __builtin_memcpy(&r, &h, 2);
  return r;
}
__device__ __forceinline__ f32x4 z4() { f32x4 z = {0.f, 0.f, 0.f, 0.f}; return z; }

// ---------------------------------------------------------------------------
// G1+G2a FUSED: per block (n, 8 t-slices = 216 p). qk = W_in@(x+pe)+b never
// leaves LDS: epilogue writes pre-frag sQF/sKF[s][u(pad32)][k=tl*16+i]
// (pitch 136 u16 -> 16B-aligned rows, ~2-way banks), then 8 waves=(s,ut,vt)
// do the 27x27 logit GEMM (K=128) and atomicAdd raw sums into att.
// Eliminates the 104 MB qG/kG HBM round-trip and one kernel launch.
// LDS: 28672 + 2*17408 = 63.5 KB -> 2 blocks/CU.
// ---------------------------------------------------------------------------
__global__ __launch_bounds__(512, 2) void g_qk_att(
    const float* __restrict__ x, const float* __restrict__ pe,
    const float* __restrict__ W_in, const float* __restrict__ b_in,
    float* __restrict__ att)
{
  __shared__ __align__(16) u16 sB16[14 * 2 * 64 * 8];  // staged (x+pe) pre-frag
  __shared__ __align__(16) u16 sQF[2][32][136];        // q^T pre-frag [s][u][k]
  __shared__ __align__(16) u16 sKF[2][32][136];        // k^T pre-frag [s][v][k]
  const int tid = threadIdx.x;
  const int w = tid >> 6, lane = tid & 63;
  const int m = lane & 15, quad = lane >> 4;
  const int ot = w & 3, g = w >> 2;
  const int n = blockIdx.y;
  const int p0 = blockIdx.x * 216;  // 8 t-slices * 27

  // persistent W_in A-frags (rows r = 16*ot+m)  [verified pattern]
  short8 aW[2];
#pragma unroll
  for (int kf = 0; kf < 2; ++kf) {
    short8 tt;
#pragma unroll
    for (int j = 0; j < 8; ++j)
      tt[j] = (short)f2u(W_in[(16 * ot + m) * 64 + 32 * kf + 8 * quad + j]);
    aW[kf] = tt;
  }
  float bb[4];
#pragma unroll
  for (int r = 0; r < 4; ++r) bb[r] = b_in[16 * ot + quad * 4 + r];

  // stage: 64c x 224pl slots (pl>=216 zero); coalesced over pl; 28 iters exact
#pragma unroll 4
  for (int i = 0; i < 28; ++i) {
    int idx = i * 512 + tid;
    int c = idx / 224, pl = idx % 224;
    float v = 0.f;
    if (pl < 216)
      v = x[(n * 64 + c) * 10800 + p0 + pl] + pe[c * 10800 + p0 + pl];
    int tile = pl >> 4, mm = pl & 15;
    int kf = c >> 5, qq = (c >> 3) & 3, j = c & 7;
    sB16[(((tile * 2 + kf) * 64) + qq * 16 + mm) * 8 + j] = f2u(v);
  }
  __syncthreads();

  // qk GEMM: wave (ot,g): ot -> 16-row tile (q s0/s1, k s0/s1); g -> 7 tiles.
  // Epilogue: rows i = quad*4+reg of block s; cols p -> (tl, u); write s4v
  // into sQF/sKF[s][u][tl*16 + i]  (k-ordering tl*16+i, same as A/B reads).
  u16* dstF = (ot < 2 ? &sQF[0][0][0] : &sKF[0][0][0]) + (ot & 1) * 32 * 136;
#pragma unroll
  for (int ti = 0; ti < 7; ++ti) {
    int tile = 7 * g + ti;
    short8 b0 = *(const short8*)&sB16[((tile * 2 + 0) * 64 + lane) * 8];
    short8 b1 = *(const short8*)&sB16[((tile * 2 + 1) * 64 + lane) * 8];
    f32x4 acc = MFMA(aW[0], b0, z4());
    acc = MFMA(aW[1], b1, acc);
    int pl = tile * 16 + m;
    if (pl < 216) {
      int tl = pl / 27, u = pl - tl * 27;
      s4v pk;
#pragma unroll
      for (int reg = 0; reg < 4; ++reg) pk[reg] = (short)f2u(acc[reg] + bb[reg]);
      *(s4v*)&dstF[u * 136 + tl * 16 + quad * 4] = pk;
    }
  }
  __syncthreads();

  // logit: wave (s,ut,vt); D[u,v] += sum_k Q[u][k]*K[v][k], K=128.
  // Rows u,v in [27,32) are uninitialized LDS -> only feed discarded D
  // rows/cols (MFMA row/col separation), masked below.
  {
    const int s = w & 1, ut = (w >> 1) & 1, vt = w >> 2;
    f32x4 acc = z4();
#pragma unroll
    for (int ks = 0; ks < 4; ++ks) {
      short8 a = *(const short8*)&sQF[s][ut * 16 + m][ks * 32 + quad * 8];
      short8 b = *(const short8*)&sKF[s][vt * 16 + m][ks * 32 + quad * 8];
      acc = MFMA(a, b, acc);
    }
#pragma unroll
    for (int reg = 0; reg < 4; ++reg) {
      int u = ut * 16 + quad * 4 + reg, v = vt * 16 + m;
      if (u < 27 && v < 27)
        atomicAdd(&att[(n * 2 + s) * 729 + u * 27 + v], acc[reg]);
    }
  }
}

// ---------------------------------------------------------------------------
// G2b: att = tanh(acc/6400)*alphas[s] + att0[s,u,v]   (in place)
// ---------------------------------------------------------------------------
__global__ __launch_bounds__(256) void k_att_fin(
    float* __restrict__ att, const float* __restrict__ alphas,
    const float* __restrict__ att0)
{
  int i = blockIdx.x * 256 + threadIdx.x;
  if (i >= 32 * 2 * 729) return;
  int s = (i / 729) & 1;
  int r = i % 729;
  att[i] = tanhf(att[i] * (1.f / 6400.f)) * alphas[s] + att0[s * 729 + r];
}

// ---------------------------------------------------------------------------
// G3 (y2+y3 fused): unchanged from r7 (measured 97.7 us — control kernel).
// ---------------------------------------------------------------------------
__global__ __launch_bounds__(512, 2) void g_ab(
    const float* __restrict__ x, const float* __restrict__ att,
    const float* __restrict__ W_out, const float* __restrict__ b_out,
    const float* __restrict__ g_out, const float* __restrict__ be_out,
    const float* __restrict__ m_out, const float* __restrict__ v_out,
    u16* __restrict__ y3T)
{
  __shared__ u32x4 sy2f[4][2][4][64];  // [t][vt][kf][lane] (32 KB)
  const int tid = threadIdx.x;
  const int w = tid >> 6, lane = tid & 63;
  const int m = lane & 15, quad = lane >> 4;
  const int ot = w & 3, g = w >> 2;
  const int n = blockIdx.y, t0 = blockIdx.x * 4;

  // hoisted loads: ax raw (phase 1) + residual x (phase 2)
  float axr[2][8];
#pragma unroll
  for (int li = 0; li < 2; ++li) {
    int t = t0 + 2 * li + g;
    const float* xp = &x[((n * 64 + 16 * ot + m) * 400 + t) * 27];
#pragma unroll
    for (int j = 0; j < 8; ++j) {
      int u = quad * 8 + j;
      axr[li][j] = (u < 27) ? xp[u] : 0.f;
    }
  }
  float xres[2][2][4];
#pragma unroll
  for (int ci = 0; ci < 2; ++ci) {
    int t = t0 + 2 * ci + g;
#pragma unroll
    for (int vt = 0; vt < 2; ++vt) {
      int v = vt * 16 + m;
#pragma unroll
      for (int reg = 0; reg < 4; ++reg) {
        int o = 16 * ot + quad * 4 + reg;
        xres[ci][vt][reg] = (v < 27) ? x[((n * 64 + o) * 400 + t) * 27 + v] : 0.f;
      }
    }
  }

  // att B-frags (same for all waves)  [verified pattern]
  short8 bAtt[4];
#pragma unroll
  for (int s = 0; s < 2; ++s)
#pragma unroll
    for (int nt = 0; nt < 2; ++nt) {
      short8 tt;
#pragma unroll
      for (int j = 0; j < 8; ++j) {
        int u = 8 * quad + j, v = 16 * nt + m;
        tt[j] = (u < 27 && v < 27) ? (short)f2u(att[(n * 2 + s) * 729 + u * 27 + v]) : (short)0;
      }
      bAtt[s * 2 + nt] = tt;
    }
  // W_out A-frags + BN consts for rows 16*ot  [verified patterns]
  short8 aWo[4];
#pragma unroll
  for (int kf = 0; kf < 4; ++kf) {
    short8 tt;
#pragma unroll
    for (int j = 0; j < 8; ++j)
      tt[j] = (short)f2u(W_out[(16 * ot + m) * 128 + 32 * kf + 8 * quad + j]);
    aWo[kf] = tt;
  }
  float Ao[4], Bo[4];
#pragma unroll
  for (int reg = 0; reg < 4; ++reg) {
    int o = 16 * ot + quad * 4 + reg;
    float sc = g_out[o] * rsqrtf(v_out[o] + EPS_);
    Ao[reg] = sc;
    Bo[reg] = (b_out[o] - m_out[o]) * sc + be_out[o];
  }

  const int q1 = quad & 1;
  const int qp = (2 * ot + (quad >> 1)) & 3;
  // phase 1: y2 frags; group g handles tc = g, g+2
#pragma unroll
  for (int li = 0; li < 2; ++li) {
    int tc = 2 * li + g;
    short8 ax;
#pragma unroll
    for (int j = 0; j < 8; ++j) ax[j] = (short)f2u(axr[li][j]);
    f32x4 acc[4];
#pragma unroll
    for (int f = 0; f < 4; ++f) acc[f] = MFMA(ax, bAtt[f], z4());
#pragma unroll
    for (int s = 0; s < 2; ++s)
#pragma unroll
      for (int nt = 0; nt < 2; ++nt) {
        f32x4 a = acc[s * 2 + nt];
        s4v pk;
#pragma unroll
        for (int reg = 0; reg < 4; ++reg) pk[reg] = (short)f2u(a[reg]);
        int kfp = 2 * s + (ot >> 1);
        *(s4v*)((u16*)&sy2f[tc][nt][kfp][qp * 16 + m] + 4 * q1) = pk;
      }
  }
  __syncthreads();
  // phase 2: y3; group g handles tc = g, g+2; residual from xres
#pragma unroll
  for (int ci = 0; ci < 2; ++ci) {
    int tc = 2 * ci + g;
    int t = t0 + tc;
#pragma unroll
    for (int vt = 0; vt < 2; ++vt) {
      f32x4 a0 = z4();
#pragma unroll
      for (int kf = 0; kf < 4; ++kf) {
        short8 b = *(const short8*)&sy2f[tc][vt][kf][lane];
        a0 = MFMA(aWo[kf], b, a0);
      }
      int v = vt * 16 + m;
      if (v < 27) {
        s4v pk;
#pragma unroll
        for (int reg = 0; reg < 4; ++reg) {
          float r = xres[ci][vt][reg] + a0[reg] * Ao[reg] + Bo[reg];
          pk[reg] = (short)f2u((r >= 0.f) ? r : LEAK * r);
        }
        *(s4v*)&y3T[(unsigned)(n * 10800 + t * 27 + v) * 64 + 16 * ot + quad * 4] = pk;
      }
    }
  }
}

// ---------------------------------------------------------------------------
// G4 (y4+z fused): unchanged from r7 (control kernel).
// ---------------------------------------------------------------------------
__global__ __launch_bounds__(512, 2) void g_cd(
    const float* __restrict__ x, const u16* __restrict__ y3T,
    const float* __restrict__ W_ff, const float* __restrict__ b_ff,
    const float* __restrict__ g_ff, const float* __restrict__ be_ff,
    const float* __restrict__ m_ff, const float* __restrict__ v_ff,
    const float* __restrict__ W_t, const float* __restrict__ b_t,
    const float* __restrict__ g_t, const float* __restrict__ be_t,
    const float* __restrict__ m_t, const float* __restrict__ v_t,
    float* __restrict__ out)
{
  __shared__ u32x4 sy4f[10][2][2][64];  // [tl][vt][ihalf][lane] (40 KB)
  const int tid = threadIdx.x;
  const int w = tid >> 6, lane = tid & 63;
  const int m = lane & 15, quad = lane >> 4;
  const int ot = w & 3, g = w >> 2;
  const int n = blockIdx.y, t0 = blockIdx.x * 8;

  short8 aWf[2], aWt[6];
#pragma unroll
  for (int kf = 0; kf < 2; ++kf) {
    short8 tt;
#pragma unroll
    for (int j = 0; j < 8; ++j)
      tt[j] = (short)f2u(W_ff[(16 * ot + m) * 64 + 32 * kf + 8 * quad + j]);
    aWf[kf] = tt;
  }
#pragma unroll
  for (int kf = 0; kf < 6; ++kf) {  // k = dt*64 + i   [verified pattern]
    short8 tt;
    int dt = kf >> 1;
#pragma unroll
    for (int j = 0; j < 8; ++j) {
      int ii = 32 * (kf & 1) + 8 * quad + j;
      tt[j] = (short)f2u(W_t[((16 * ot + m) * 64 + ii) * 3 + dt]);
    }
    aWt[kf] = tt;
  }
  float Af[4], Bf[4], At[4], Bt[4];
#pragma unroll
  for (int reg = 0; reg < 4; ++reg) {
    int o = 16 * ot + quad * 4 + reg;
    float sc;
    sc = g_ff[o] * rsqrtf(v_ff[o] + EPS_); Af[reg] = sc; Bf[reg] = (b_ff[o] - m_ff[o]) * sc + be_ff[o];
    sc = g_t[o] * rsqrtf(v_t[o] + EPS_);   At[reg] = sc; Bt[reg] = (b_t[o] - m_t[o]) * sc + be_t[o];
  }

  const int q1 = quad & 1;
  const int qp = (2 * ot + (quad >> 1)) & 3;
  const int kfp = ot >> 1;
  // phase 1: y4 frags; group g handles tl = g, g+2, ..., g+8 (5 each);
  // loads for both vt issued before compute
#pragma unroll
  for (int li = 0; li < 5; ++li) {
    int tl = 2 * li + g;
    int t = t0 - 1 + tl;
    if (t >= 0 && t < 400) {
      short8 yb[2][2];
      float xr[2][4];
#pragma unroll
      for (int vt = 0; vt < 2; ++vt) {
        int v = vt * 16 + m;
        unsigned p = (unsigned)(n * 10800 + t * 27 + v);  // v>=27 spill benign
        yb[vt][0] = *(const short8*)&y3T[p * 64 + quad * 8];
        yb[vt][1] = *(const short8*)&y3T[p * 64 + 32 + quad * 8];
#pragma unroll
        for (int reg = 0; reg < 4; ++reg) {
          int o = 16 * ot + quad * 4 + reg;
          xr[vt][reg] = (v < 27) ? x[((n * 64 + o) * 400 + t) * 27 + v] : 0.f;
        }
      }
#pragma unroll
      for (int vt = 0; vt < 2; ++vt) {
        f32x4 acc = MFMA(aWf[0], yb[vt][0], z4());
        acc = MFMA(aWf[1], yb[vt][1], acc);
        s4v pk;
#pragma unroll
        for (int reg = 0; reg < 4; ++reg) {
          float r = xr[vt][reg] + acc[reg] * Af[reg] + Bf[reg];
          pk[reg] = (short)f2u((r >= 0.f) ? r : LEAK * r);
        }
        *(s4v*)((u16*)&sy4f[tl][vt][kfp][qp * 16 + m] + 4 * q1) = pk;
      }
    } else {
      s4v zz = {0, 0, 0, 0};
#pragma unroll
      for (int vt = 0; vt < 2; ++vt)
        *(s4v*)((u16*)&sy4f[tl][vt][kfp][qp * 16 + m] + 4 * q1) = zz;
    }
  }
  __syncthreads();
  // phase 2: conv + residual; group g handles tc = g, g+2, g+4, g+6
#pragma unroll
  for (int ci = 0; ci < 4; ++ci) {
    int tc = 2 * ci + g;
    int t = t0 + tc;
#pragma unroll
    for (int vt = 0; vt < 2; ++vt) {
      f32x4 acc = z4();
#pragma unroll
      for (int kf = 0; kf < 6; ++kf) {
        short8 b = *(const short8*)&sy4f[tc + (kf >> 1)][vt][kf & 1][lane];
        acc = MFMA(aWt[kf], b, acc);
      }
      int v = vt * 16 + m;
      if (v < 27) {
        // residual y4[o][v][tl=tc+1]: same (ot,quad,m) half-slot indexing
        s4v res = *(const s4v*)((const u16*)&sy4f[tc + 1][vt][kfp][qp * 16 + m] + 4 * q1);
#pragma unroll
        for (int reg = 0; reg < 4; ++reg) {
          int o = 16 * ot + quad * 4 + reg;
          float r = u2f((u16)res[reg]) + acc[reg] * At[reg] + Bt[reg];
          out[((n * 64 + o) * 400 + t) * 27 + v] = (r >= 0.f) ? r : LEAK * r;
        }
      }
    }
  }
}

// ---------------------------------------------------------------------------
extern "C" void kernel_launch(void* const* d_in, const int* in_sizes, int n_in,
                              void* d_out, int out_size, void* d_ws, size_t ws_size,
                              hipStream_t stream)
{
  const float* x      = (const float*)d_in[0];
  const float* pe     = (const float*)d_in[1];
  const float* W_in   = (const float*)d_in[2];
  const float* b_in   = (const float*)d_in[3];
  const float* alphas = (const float*)d_in[4];
  const float* att0   = (const float*)d_in[5];
  const float* W_out  = (const float*)d_in[6];
  const float* b_out  = (const float*)d_in[7];
  const float* g_out  = (const float*)d_in[8];
  const float* be_out = (const float*)d_in[9];
  const float* m_out  = (const float*)d_in[10];
  const float* v_out  = (const float*)d_in[11];
  const float* W_ff   = (const float*)d_in[12];
  const float* b_ff   = (const float*)d_in[13];
  const float* g_ff   = (const float*)d_in[14];
  const float* be_ff  = (const float*)d_in[15];
  const float* m_ff   = (const float*)d_in[16];
  const float* v_ff   = (const float*)d_in[17];
  const float* W_t    = (const float*)d_in[18];
  const float* b_t    = (const float*)d_in[19];
  const float* g_t    = (const float*)d_in[20];
  const float* be_t   = (const float*)d_in[21];
  const float* m_t    = (const float*)d_in[22];
  const float* v_t    = (const float*)d_in[23];

  // workspace layout (shrunk: qG/kG eliminated by the qk+att fusion):
  //   [0, 186624)        att f32 [32][2][27][27] (raw logit sums -> final)
  //   [1MB, 1MB+44.2MB)  y3T bf16 [345600][64]
  float* att = (float*)d_ws;
  u16* y3T = (u16*)((char*)d_ws + (1u << 20));

  hipMemsetAsync(att, 0, 32 * 2 * 729 * sizeof(float), stream);
  g_qk_att<<<dim3(50, 32), 512, 0, stream>>>(x, pe, W_in, b_in, att);
  k_att_fin<<<dim3(183), 256, 0, stream>>>(att, alphas, att0);
  g_ab<<<dim3(100, 32), 512, 0, stream>>>(
      x, att, W_out, b_out, g_out, be_out, m_out, v_out, y3T);
  g_cd<<<dim3(50, 32), 512, 0, stream>>>(
      x, y3T, W_ff, b_ff, g_ff, be_ff, m_ff, v_ff,
      W_t, b_t, g_t, be_t, m_t, v_t, (float*)d_out);
}

// Round 9
// 404.660 us; speedup vs baseline: 1.0647x; 1.0647x over previous
//
#include <hip/hip_runtime.h>
#include <hip/hip_bf16.h>

typedef __hip_bfloat16 bf16;
typedef unsigned short u16;
typedef __attribute__((ext_vector_type(8))) short short8;
typedef __attribute__((ext_vector_type(4))) short s4v;
typedef __attribute__((ext_vector_type(4))) float f32x4;
typedef __attribute__((ext_vector_type(4))) unsigned int u32x4;

#define LEAK 0.1f
#define EPS_ 1e-5f
#define MFMA(a, b, c) __builtin_amdgcn_mfma_f32_16x16x32_bf16(a, b, c, 0, 0, 0)
// N=32 C=64 T=400 V=27 S=2 IC=16 O=64; P = T*V = 10800 per n.

__device__ __forceinline__ float u2f(u16 u) { return __uint_as_float(((unsigned int)u) << 16); }
__device__ __forceinline__ u16 f2u(float f) {
  bf16 h = __float2bfloat16(f);
  u16 r;
  __builtin_memcpy(&r, &h, 2);
  return r;
}
__device__ __forceinline__ f32x4 z4() { f32x4 z = {0.f, 0.f, 0.f, 0.f}; return z; }

// ---------------------------------------------------------------------------
// G1+G2a FUSED (unchanged from r8 — control): qk stays in LDS, logit GEMM
// + atomicAdd raw sums.
// ---------------------------------------------------------------------------
__global__ __launch_bounds__(512, 2) void g_qk_att(
    const float* __restrict__ x, const float* __restrict__ pe,
    const float* __restrict__ W_in, const float* __restrict__ b_in,
    float* __restrict__ att)
{
  __shared__ __align__(16) u16 sB16[14 * 2 * 64 * 8];  // staged (x+pe) pre-frag
  __shared__ __align__(16) u16 sQF[2][32][136];        // q^T pre-frag [s][u][k]
  __shared__ __align__(16) u16 sKF[2][32][136];        // k^T pre-frag [s][v][k]
  const int tid = threadIdx.x;
  const int w = tid >> 6, lane = tid & 63;
  const int m = lane & 15, quad = lane >> 4;
  const int ot = w & 3, g = w >> 2;
  const int n = blockIdx.y;
  const int p0 = blockIdx.x * 216;  // 8 t-slices * 27

  short8 aW[2];
#pragma unroll
  for (int kf = 0; kf < 2; ++kf) {
    short8 tt;
#pragma unroll
    for (int j = 0; j < 8; ++j)
      tt[j] = (short)f2u(W_in[(16 * ot + m) * 64 + 32 * kf + 8 * quad + j]);
    aW[kf] = tt;
  }
  float bb[4];
#pragma unroll
  for (int r = 0; r < 4; ++r) bb[r] = b_in[16 * ot + quad * 4 + r];

#pragma unroll 4
  for (int i = 0; i < 28; ++i) {
    int idx = i * 512 + tid;
    int c = idx / 224, pl = idx % 224;
    float v = 0.f;
    if (pl < 216)
      v = x[(n * 64 + c) * 10800 + p0 + pl] + pe[c * 10800 + p0 + pl];
    int tile = pl >> 4, mm = pl & 15;
    int kf = c >> 5, qq = (c >> 3) & 3, j = c & 7;
    sB16[(((tile * 2 + kf) * 64) + qq * 16 + mm) * 8 + j] = f2u(v);
  }
  __syncthreads();

  u16* dstF = (ot < 2 ? &sQF[0][0][0] : &sKF[0][0][0]) + (ot & 1) * 32 * 136;
#pragma unroll
  for (int ti = 0; ti < 7; ++ti) {
    int tile = 7 * g + ti;
    short8 b0 = *(const short8*)&sB16[((tile * 2 + 0) * 64 + lane) * 8];
    short8 b1 = *(const short8*)&sB16[((tile * 2 + 1) * 64 + lane) * 8];
    f32x4 acc = MFMA(aW[0], b0, z4());
    acc = MFMA(aW[1], b1, acc);
    int pl = tile * 16 + m;
    if (pl < 216) {
      int tl = pl / 27, u = pl - tl * 27;
      s4v pk;
#pragma unroll
      for (int reg = 0; reg < 4; ++reg) pk[reg] = (short)f2u(acc[reg] + bb[reg]);
      *(s4v*)&dstF[u * 136 + tl * 16 + quad * 4] = pk;
    }
  }
  __syncthreads();

  {
    const int s = w & 1, ut = (w >> 1) & 1, vt = w >> 2;
    f32x4 acc = z4();
#pragma unroll
    for (int ks = 0; ks < 4; ++ks) {
      short8 a = *(const short8*)&sQF[s][ut * 16 + m][ks * 32 + quad * 8];
      short8 b = *(const short8*)&sKF[s][vt * 16 + m][ks * 32 + quad * 8];
      acc = MFMA(a, b, acc);
    }
#pragma unroll
    for (int reg = 0; reg < 4; ++reg) {
      int u = ut * 16 + quad * 4 + reg, v = vt * 16 + m;
      if (u < 27 && v < 27)
        atomicAdd(&att[(n * 2 + s) * 729 + u * 27 + v], acc[reg]);
    }
  }
}

// ---------------------------------------------------------------------------
// G2b: att = tanh(acc/6400)*alphas[s] + att0[s,u,v]   (in place)
// ---------------------------------------------------------------------------
__global__ __launch_bounds__(256) void k_att_fin(
    float* __restrict__ att, const float* __restrict__ alphas,
    const float* __restrict__ att0)
{
  int i = blockIdx.x * 256 + threadIdx.x;
  if (i >= 32 * 2 * 729) return;
  int s = (i / 729) & 1;
  int r = i % 729;
  att[i] = tanhf(att[i] * (1.f / 6400.f)) * alphas[s] + att0[s * 729 + r];
}

// ---------------------------------------------------------------------------
// G3 (y2+y3 fused), COALESCED-STAGING version. Single mechanism change vs r8:
// ALL global reads of x and att are replaced by one coalesced LDS staging
// pass (f32x4 for x: each channel's 4-slice row is 108 contiguous floats,
// 16B-aligned since t0%4==0). axr/bAtt/xres then read LDS (<=2-way banks).
// Cuts per-block cache-line requests ~8x (was ~4K lines via per-lane 43KB-
// strided scalar loads). Residual stays f32 -> numerics identical.
// LDS: 27.8 + 5.9 + 32 KB = 66.4 KB -> 2 blocks/CU.
// ---------------------------------------------------------------------------
__global__ __launch_bounds__(512, 2) void g_ab(
    const float* __restrict__ x, const float* __restrict__ att,
    const float* __restrict__ W_out, const float* __restrict__ b_out,
    const float* __restrict__ g_out, const float* __restrict__ be_out,
    const float* __restrict__ m_out, const float* __restrict__ v_out,
    u16* __restrict__ y3T)
{
  __shared__ __align__(16) float sxf[6944];   // [c][t*27+v] (+pad)
  __shared__ __align__(16) float satt[1464];  // [s*729 + u*27 + v]
  __shared__ u32x4 sy2f[4][2][4][64];         // [t][vt][kf][lane] (32 KB)
  const int tid = threadIdx.x;
  const int w = tid >> 6, lane = tid & 63;
  const int m = lane & 15, quad = lane >> 4;
  const int ot = w & 3, g = w >> 2;
  const int n = blockIdx.y, t0 = blockIdx.x * 4;

  // W_out A-frags + BN consts (global; issued ahead of staging)
  short8 aWo[4];
#pragma unroll
  for (int kf = 0; kf < 4; ++kf) {
    short8 tt;
#pragma unroll
    for (int j = 0; j < 8; ++j)
      tt[j] = (short)f2u(W_out[(16 * ot + m) * 128 + 32 * kf + 8 * quad + j]);
    aWo[kf] = tt;
  }
  float Ao[4], Bo[4];
#pragma unroll
  for (int reg = 0; reg < 4; ++reg) {
    int o = 16 * ot + quad * 4 + reg;
    float sc = g_out[o] * rsqrtf(v_out[o] + EPS_);
    Ao[reg] = sc;
    Bo[reg] = (b_out[o] - m_out[o]) * sc + be_out[o];
  }

  // stage x-tile: 1728 f32x4 units; consecutive tid -> consecutive 16B within
  // a channel's contiguous 108-float run (t0*27 .. t0*27+107). Coalesced.
  for (int i = tid; i < 1728; i += 512) {
    int c = i / 27, q = i - c * 27;
    f32x4 tv = *(const f32x4*)&x[(n * 64 + c) * 10800 + t0 * 27 + q * 4];
    *(f32x4*)&sxf[c * 108 + q * 4] = tv;
  }
  // stage att (both s): coalesced scalar
  for (int i = tid; i < 1458; i += 512) satt[i] = att[n * 1458 + i];
  __syncthreads();

  // bAtt frags from LDS  [same values as verified pattern]
  short8 bAtt[4];
#pragma unroll
  for (int s = 0; s < 2; ++s)
#pragma unroll
    for (int nt = 0; nt < 2; ++nt) {
      short8 tt;
#pragma unroll
      for (int j = 0; j < 8; ++j) {
        int u = 8 * quad + j, v = 16 * nt + m;
        tt[j] = (u < 27 && v < 27) ? (short)f2u(satt[s * 729 + u * 27 + v]) : (short)0;
      }
      bAtt[s * 2 + nt] = tt;
    }

  const int q1 = quad & 1;
  const int qp = (2 * ot + (quad >> 1)) & 3;
  // phase 1: y2 frags; group g handles tc = g, g+2; ax from LDS
#pragma unroll
  for (int li = 0; li < 2; ++li) {
    int tc = 2 * li + g;
    short8 ax;
#pragma unroll
    for (int j = 0; j < 8; ++j) {
      int u = quad * 8 + j;
      ax[j] = (u < 27) ? (short)f2u(sxf[(16 * ot + m) * 108 + tc * 27 + u]) : (short)0;
    }
    f32x4 acc[4];
#pragma unroll
    for (int f = 0; f < 4; ++f) acc[f] = MFMA(ax, bAtt[f], z4());
#pragma unroll
    for (int s = 0; s < 2; ++s)
#pragma unroll
      for (int nt = 0; nt < 2; ++nt) {
        f32x4 a = acc[s * 2 + nt];
        s4v pk;
#pragma unroll
        for (int reg = 0; reg < 4; ++reg) pk[reg] = (short)f2u(a[reg]);
        int kfp = 2 * s + (ot >> 1);
        *(s4v*)((u16*)&sy2f[tc][nt][kfp][qp * 16 + m] + 4 * q1) = pk;
      }
  }
  __syncthreads();
  // phase 2: y3; group g handles tc = g, g+2; residual from LDS (f32 exact)
#pragma unroll
  for (int ci = 0; ci < 2; ++ci) {
    int tc = 2 * ci + g;
    int t = t0 + tc;
#pragma unroll
    for (int vt = 0; vt < 2; ++vt) {
      f32x4 a0 = z4();
#pragma unroll
      for (int kf = 0; kf < 4; ++kf) {
        short8 b = *(const short8*)&sy2f[tc][vt][kf][lane];
        a0 = MFMA(aWo[kf], b, a0);
      }
      int v = vt * 16 + m;
      if (v < 27) {
        s4v pk;
#pragma unroll
        for (int reg = 0; reg < 4; ++reg) {
          int o = 16 * ot + quad * 4 + reg;
          float r = sxf[o * 108 + tc * 27 + v] + a0[reg] * Ao[reg] + Bo[reg];
          pk[reg] = (short)f2u((r >= 0.f) ? r : LEAK * r);
        }
        *(s4v*)&y3T[(unsigned)(n * 10800 + t * 27 + v) * 64 + 16 * ot + quad * 4] = pk;
      }
    }
  }
}

// ---------------------------------------------------------------------------
// G4 (y4+z fused): unchanged from r8 (control kernel).
// ---------------------------------------------------------------------------
__global__ __launch_bounds__(512, 2) void g_cd(
    const float* __restrict__ x, const u16* __restrict__ y3T,
    const float* __restrict__ W_ff, const float* __restrict__ b_ff,
    const float* __restrict__ g_ff, const float* __restrict__ be_ff,
    const float* __restrict__ m_ff, const float* __restrict__ v_ff,
    const float* __restrict__ W_t, const float* __restrict__ b_t,
    const float* __restrict__ g_t, const float* __restrict__ be_t,
    const float* __restrict__ m_t, const float* __restrict__ v_t,
    float* __restrict__ out)
{
  __shared__ u32x4 sy4f[10][2][2][64];  // [tl][vt][ihalf][lane] (40 KB)
  const int tid = threadIdx.x;
  const int w = tid >> 6, lane = tid & 63;
  const int m = lane & 15, quad = lane >> 4;
  const int ot = w & 3, g = w >> 2;
  const int n = blockIdx.y, t0 = blockIdx.x * 8;

  short8 aWf[2], aWt[6];
#pragma unroll
  for (int kf = 0; kf < 2; ++kf) {
    short8 tt;
#pragma unroll
    for (int j = 0; j < 8; ++j)
      tt[j] = (short)f2u(W_ff[(16 * ot + m) * 64 + 32 * kf + 8 * quad + j]);
    aWf[kf] = tt;
  }
#pragma unroll
  for (int kf = 0; kf < 6; ++kf) {  // k = dt*64 + i   [verified pattern]
    short8 tt;
    int dt = kf >> 1;
#pragma unroll
    for (int j = 0; j < 8; ++j) {
      int ii = 32 * (kf & 1) + 8 * quad + j;
      tt[j] = (short)f2u(W_t[((16 * ot + m) * 64 + ii) * 3 + dt]);
    }
    aWt[kf] = tt;
  }
  float Af[4], Bf[4], At[4], Bt[4];
#pragma unroll
  for (int reg = 0; reg < 4; ++reg) {
    int o = 16 * ot + quad * 4 + reg;
    float sc;
    sc = g_ff[o] * rsqrtf(v_ff[o] + EPS_); Af[reg] = sc; Bf[reg] = (b_ff[o] - m_ff[o]) * sc + be_ff[o];
    sc = g_t[o] * rsqrtf(v_t[o] + EPS_);   At[reg] = sc; Bt[reg] = (b_t[o] - m_t[o]) * sc + be_t[o];
  }

  const int q1 = quad & 1;
  const int qp = (2 * ot + (quad >> 1)) & 3;
  const int kfp = ot >> 1;
  // phase 1: y4 frags; group g handles tl = g, g+2, ..., g+8 (5 each);
  // loads for both vt issued before compute
#pragma unroll
  for (int li = 0; li < 5; ++li) {
    int tl = 2 * li + g;
    int t = t0 - 1 + tl;
    if (t >= 0 && t < 400) {
      short8 yb[2][2];
      float xr[2][4];
#pragma unroll
      for (int vt = 0; vt < 2; ++vt) {
        int v = vt * 16 + m;
        unsigned p = (unsigned)(n * 10800 + t * 27 + v);  // v>=27 spill benign
        yb[vt][0] = *(const short8*)&y3T[p * 64 + quad * 8];
        yb[vt][1] = *(const short8*)&y3T[p * 64 + 32 + quad * 8];
#pragma unroll
        for (int reg = 0; reg < 4; ++reg) {
          int o = 16 * ot + quad * 4 + reg;
          xr[vt][reg] = (v < 27) ? x[((n * 64 + o) * 400 + t) * 27 + v] : 0.f;
        }
      }
#pragma unroll
      for (int vt = 0; vt < 2; ++vt) {
        f32x4 acc = MFMA(aWf[0], yb[vt][0], z4());
        acc = MFMA(aWf[1], yb[vt][1], acc);
        s4v pk;
#pragma unroll
        for (int reg = 0; reg < 4; ++reg) {
          float r = xr[vt][reg] + acc[reg] * Af[reg] + Bf[reg];
          pk[reg] = (short)f2u((r >= 0.f) ? r : LEAK * r);
        }
        *(s4v*)((u16*)&sy4f[tl][vt][kfp][qp * 16 + m] + 4 * q1) = pk;
      }
    } else {
      s4v zz = {0, 0, 0, 0};
#pragma unroll
      for (int vt = 0; vt < 2; ++vt)
        *(s4v*)((u16*)&sy4f[tl][vt][kfp][qp * 16 + m] + 4 * q1) = zz;
    }
  }
  __syncthreads();
  // phase 2: conv + residual; group g handles tc = g, g+2, g+4, g+6
#pragma unroll
  for (int ci = 0; ci < 4; ++ci) {
    int tc = 2 * ci + g;
    int t = t0 + tc;
#pragma unroll
    for (int vt = 0; vt < 2; ++vt) {
      f32x4 acc = z4();
#pragma unroll
      for (int kf = 0; kf < 6; ++kf) {
        short8 b = *(const short8*)&sy4f[tc + (kf >> 1)][vt][kf & 1][lane];
        acc = MFMA(aWt[kf], b, acc);
      }
      int v = vt * 16 + m;
      if (v < 27) {
        // residual y4[o][v][tl=tc+1]: same (ot,quad,m) half-slot indexing
        s4v res = *(const s4v*)((const u16*)&sy4f[tc + 1][vt][kfp][qp * 16 + m] + 4 * q1);
#pragma unroll
        for (int reg = 0; reg < 4; ++reg) {
          int o = 16 * ot + quad * 4 + reg;
          float r = u2f((u16)res[reg]) + acc[reg] * At[reg] + Bt[reg];
          out[((n * 64 + o) * 400 + t) * 27 + v] = (r >= 0.f) ? r : LEAK * r;
        }
      }
    }
  }
}

// ---------------------------------------------------------------------------
extern "C" void kernel_launch(void* const* d_in, const int* in_sizes, int n_in,
                              void* d_out, int out_size, void* d_ws, size_t ws_size,
                              hipStream_t stream)
{
  const float* x      = (const float*)d_in[0];
  const float* pe     = (const float*)d_in[1];
  const float* W_in   = (const float*)d_in[2];
  const float* b_in   = (const float*)d_in[3];
  const float* alphas = (const float*)d_in[4];
  const float* att0   = (const float*)d_in[5];
  const float* W_out  = (const float*)d_in[6];
  const float* b_out  = (const float*)d_in[7];
  const float* g_out  = (const float*)d_in[8];
  const float* be_out = (const float*)d_in[9];
  const float* m_out  = (const float*)d_in[10];
  const float* v_out  = (const float*)d_in[11];
  const float* W_ff   = (const float*)d_in[12];
  const float* b_ff   = (const float*)d_in[13];
  const float* g_ff   = (const float*)d_in[14];
  const float* be_ff  = (const float*)d_in[15];
  const float* m_ff   = (const float*)d_in[16];
  const float* v_ff   = (const float*)d_in[17];
  const float* W_t    = (const float*)d_in[18];
  const float* b_t    = (const float*)d_in[19];
  const float* g_t    = (const float*)d_in[20];
  const float* be_t   = (const float*)d_in[21];
  const float* m_t    = (const float*)d_in[22];
  const float* v_t    = (const float*)d_in[23];

  // workspace layout:
  //   [0, 186624)        att f32 [32][2][27][27] (raw logit sums -> final)
  //   [1MB, 1MB+44.2MB)  y3T bf16 [345600][64]
  float* att = (float*)d_ws;
  u16* y3T = (u16*)((char*)d_ws + (1u << 20));

  hipMemsetAsync(att, 0, 32 * 2 * 729 * sizeof(float), stream);
  g_qk_att<<<dim3(50, 32), 512, 0, stream>>>(x, pe, W_in, b_in, att);
  k_att_fin<<<dim3(183), 256, 0, stream>>>(att, alphas, att0);
  g_ab<<<dim3(100, 32), 512, 0, stream>>>(
      x, att, W_out, b_out, g_out, be_out, m_out, v_out, y3T);
  g_cd<<<dim3(50, 32), 512, 0, stream>>>(
      x, y3T, W_ff, b_ff, g_ff, be_ff, m_ff, v_ff,
      W_t, b_t, g_t, be_t, m_t, v_t, (float*)d_out);
}